// Round 12
// baseline (187.194 us; speedup 1.0000x reference)
//
#include <hip/hip_runtime.h>
#include <hip/hip_fp16.h>

typedef _Float16 half8 __attribute__((ext_vector_type(8)));
typedef _Float16 half4v __attribute__((ext_vector_type(4)));
typedef float floatx4 __attribute__((ext_vector_type(4)));

#define HW 128
#define IMG (HW * HW)
#define PH 130          // padded height/width
#define XP 164          // conv_c160 xs pitch (verified conflict fix, r4)

// async global->LDS, 16 B/lane: LDS dest = wave-uniform base + lane*16.
typedef __attribute__((address_space(3))) _Float16 lds_f16;
typedef __attribute__((address_space(1))) const _Float16 glb_f16;
__device__ __forceinline__ void gload16(const _Float16* g, _Float16* l) {
    __builtin_amdgcn_global_load_lds((glb_f16*)g, (lds_f16*)l, 16, 0, 0);
}

// ---------------------------------------------------------------------------
// pack all weights in ONE dispatch -- ALL layers FRAGMENT-ORDERED for direct
// register loads (r3-verified mechanism):
// w0: W0f[oh][frag=(t*5+cb)*2+n][lane][8]
// w1/w2: W1f[oh][frag=t*4+cb*2+n][lane][8]
// wl: WLf[g=of/48][frag=t*2+cb][n][lane][8]  (48-out groups; byte-identical
//     to r9's layout -- the 144-out head tile consumes g = ct*3+og)
// ---------------------------------------------------------------------------
__global__ void pack_w_all(const float* __restrict__ w0, const float* __restrict__ w1,
                           const float* __restrict__ w2, const float* __restrict__ wl,
                           _Float16* __restrict__ p0, _Float16* __restrict__ p1,
                           _Float16* __restrict__ p2, _Float16* __restrict__ pl) {
    int idx = blockIdx.x * 256 + threadIdx.x;
    if (idx < 92160) {
        int local = idx;
        int o = local / 1440;          // 160*9
        int rem = local % 1440;
        int c = rem / 9;
        int t = rem % 9;
        int oh = o >> 5, n = (o >> 4) & 1, l15 = o & 15;
        int cb = c >> 5, l4 = (c >> 3) & 3, e = c & 7;
        int frag = (t * 5 + cb) * 2 + n;
        p0[(size_t)oh * 46080 + frag * 512 + (l4 * 16 + l15) * 8 + e] =
            (_Float16)w0[local];
        return;
    }
    if (idx < 165888) {                // w1 / w2: O=64, C=64
        const float* w; _Float16* p; int local;
        if (idx < 129024) { w = w1; p = p1; local = idx - 92160; }
        else              { w = w2; p = p2; local = idx - 129024; }
        int o = local / 576;
        int rem = local % 576;
        int c = rem / 9;
        int t = rem % 9;               // t = r*3+dw
        int oh = o >> 5, n = (o >> 4) & 1, l15 = o & 15;
        int cb = c >> 5, l4 = (c >> 3) & 3, e = c & 7;
        int frag = t * 4 + cb * 2 + n; // 36 frags
        p[(size_t)oh * 18432 + frag * 512 + (l4 * 16 + l15) * 8 + e] =
            (_Float16)w[local];
        return;
    }
    if (idx < 331776) {                // wl: O=288, C=64
        int local = idx - 165888;
        int of = local / 576;
        int rem = local % 576;
        int c = rem / 9;
        int t = rem % 9;
        int g = of / 48;               // 48-out group 0..5
        int n = (of % 48) / 16;
        int l15 = of & 15;
        int j = c >> 3;                // 0..7 c-block
        int cb = j >> 2, l4 = j & 3, e = c & 7;
        int frag = t * 2 + cb;         // 18 frags
        pl[((((size_t)g * 18 + frag) * 3 + n) * 64
            + (l4 * 16 + l15)) * 8 + e] = (_Float16)wl[local];
    }
}

// ---------------------------------------------------------------------------
// zero 1-px halo of padded NHWC tensors
// ---------------------------------------------------------------------------
__device__ __forceinline__ void zero_halo(_Float16* P, int C, int id) {
    int nvec = C / 8;
    int b = id / (516 * nvec);
    int r = id % (516 * nvec);
    int cell = r / nvec;
    int v = r % nvec;
    int hh, ww;
    if (cell < 130)      { hh = 0;   ww = cell; }
    else if (cell < 260) { hh = 129; ww = cell - 130; }
    else if (cell < 388) { hh = cell - 260 + 1; ww = 0; }
    else                 { hh = cell - 388 + 1; ww = 129; }
    half8 z8 = {};
    *reinterpret_cast<half8*>(P + (((size_t)b * PH + hh) * PH + ww) * C + v * 8) = z8;
}

__global__ void zero_pads_pre(_Float16* __restrict__ X0, _Float16* __restrict__ Q1) {
    int id = blockIdx.x * 256 + threadIdx.x;     // 82560 + 33024
    if (id < 82560) zero_halo(X0, 160, id);
    else if (id < 115584) zero_halo(Q1, 64, id - 82560);
}

__global__ void zero_pads64(_Float16* __restrict__ P) {
    int id = blockIdx.x * 256 + threadIdx.x;
    if (id < 33024) zero_halo(P, 64, id);
}

// ---------------------------------------------------------------------------
// pack input -> X0 padded NHWC f16 [b][130][130][160] (interior)
// ---------------------------------------------------------------------------
__global__ __launch_bounds__(256)
void pack_in(const float* __restrict__ z, const float* __restrict__ bb,
             const float* __restrict__ ms, const float* __restrict__ mu,
             _Float16* __restrict__ X0) {
    __shared__ _Float16 lds[160 * 132];
    int b = blockIdx.x >> 7;
    int h = blockIdx.x & 127;
    int tid = threadIdx.x;

    for (int i = 0; i < 20; i++) {
        int id = i * 256 + tid;
        int c = id >> 5;
        int col = (id & 31) * 4;
        const float* src; int cs; int csz;
        if (c < 64)       { src = bb; cs = c;       csz = 64; }
        else if (c < 96)  { src = z;  cs = c - 64;  csz = 32; }
        else if (c < 128) { src = ms; cs = c - 96;  csz = 32; }
        else              { src = mu; cs = c - 128; csz = 32; }
        float4 v = *reinterpret_cast<const float4*>(
            src + ((size_t)b * csz + cs) * IMG + h * HW + col);
        half4v hv = { (_Float16)v.x, (_Float16)v.y, (_Float16)v.z, (_Float16)v.w };
        *reinterpret_cast<half4v*>(&lds[c * 132 + col]) = hv;
    }
    __syncthreads();
    _Float16* dst = X0 + (((size_t)b * PH + (h + 1)) * PH + 1) * 160;
    for (int i = 0; i < 10; i++) {
        int id = i * 256 + tid;
        int pix = id / 20;
        int c0 = (id % 20) * 8;
        half8 hv;
        #pragma unroll
        for (int e = 0; e < 8; e++) hv[e] = lds[(c0 + e) * 132 + pix];
        *reinterpret_cast<half8*>(dst + (size_t)pix * 160 + c0) = hv;
    }
}

// ---------------------------------------------------------------------------
// conv0: CIN=160. r9-verified form (~42.9 us): full-row blocks, grid 1024,
// SA/SB register weight ping-pong, fragment-ordered weights, XP=164, (256,2).
// ---------------------------------------------------------------------------
__global__ __launch_bounds__(256, 2)
void conv3_c160(const _Float16* __restrict__ X, const _Float16* __restrict__ Wp,
                const float* __restrict__ bias, _Float16* __restrict__ Y) {
    __shared__ _Float16 xs[130 * XP];   // 42640 B
    int b = blockIdx.x >> 7;
    int h = blockIdx.x & 127;
    int tid = threadIdx.x;
    int lane = tid & 63;
    int wave = tid >> 6;
    int ph = wave & 1;
    int oh = wave >> 1;
    int l15 = lane & 15;
    int l4  = lane >> 4;

    floatx4 acc[4][2] = {};
    half8 SA[10], SB[10];   // ping-pong weight slices: 10 half8 = 40 VGPR each

    const _Float16* wl = Wp + (size_t)oh * 46080 + lane * 8;

#define LOADW(S, k) { \
    _Pragma("unroll") \
    for (int cb = 0; cb < 5; cb++) \
      _Pragma("unroll") \
      for (int n = 0; n < 2; n++) \
        S[cb * 2 + n] = *reinterpret_cast<const half8*>( \
            wl + (size_t)(((k) * 5 + cb) * 2 + n) * 512); }

#define STAGE160(r) { \
    const _Float16* grow = X + ((size_t)b * PH + (h + (r))) * PH * 160; \
    _Pragma("unroll") \
    for (int i = 0; i < 11; i++) { \
      int id = i * 256 + tid; \
      if (id < 2600) { \
        half8 v = *reinterpret_cast<const half8*>(grow + (size_t)id * 8); \
        *reinterpret_cast<half8*>(&xs[(id / 20) * XP + (id % 20) * 8]) = v; \
      } } }

#define COMP160(dw, S) { \
    _Pragma("unroll") \
    for (int cb = 0; cb < 5; cb++) { \
      int kofs = cb * 32 + l4 * 8; \
      half8 af[4]; \
      _Pragma("unroll") \
      for (int m = 0; m < 4; m++) { \
        int p = ph * 64 + m * 16 + l15; \
        af[m] = *reinterpret_cast<const half8*>(&xs[(p + (dw)) * XP + kofs]); \
      } \
      _Pragma("unroll") \
      for (int m = 0; m < 4; m++) \
        _Pragma("unroll") \
        for (int n = 0; n < 2; n++) \
          acc[m][n] = __builtin_amdgcn_mfma_f32_16x16x32_f16( \
              af[m], S[cb * 2 + n], acc[m][n], 0, 0, 0); } }

    LOADW(SA, 0);
    STAGE160(0);
    __syncthreads();
    LOADW(SB, 1);  COMP160(0, SA);
    LOADW(SA, 2);  COMP160(1, SB);
    LOADW(SB, 3);  COMP160(2, SA);
    __syncthreads();
    STAGE160(1);
    __syncthreads();
    LOADW(SA, 4);  COMP160(0, SB);
    LOADW(SB, 5);  COMP160(1, SA);
    LOADW(SA, 6);  COMP160(2, SB);
    __syncthreads();
    STAGE160(2);
    __syncthreads();
    LOADW(SB, 7);  COMP160(0, SA);
    LOADW(SA, 8);  COMP160(1, SB);
    COMP160(2, SA);

#undef LOADW
#undef STAGE160
#undef COMP160

    _Float16* dst = Y + (((size_t)b * PH + (h + 1)) * PH + 1) * 64;
    #pragma unroll
    for (int m = 0; m < 4; m++)
        #pragma unroll
        for (int n = 0; n < 2; n++) {
            int o = oh * 32 + n * 16 + l15;
            float bv = bias[o];
            #pragma unroll
            for (int q = 0; q < 4; q++) {
                int pix = ph * 64 + m * 16 + l4 * 4 + q;
                float v = acc[m][n][q] + bv;
                v = v > 0.f ? v : 0.01f * v;
                dst[(size_t)pix * 64 + o] = (_Float16)v;
            }
        }
}

// ---------------------------------------------------------------------------
// conv_c64 v2 (r9-verified): REGISTER-W, no wbuf LDS. (256,2).
// ---------------------------------------------------------------------------
__global__ __launch_bounds__(256, 2)
void conv3_c64(const _Float16* __restrict__ X, const _Float16* __restrict__ Wp,
               const float* __restrict__ bias, _Float16* __restrict__ Y) {
    __shared__ _Float16 xs[130 * 72];   // 18720 B
    int b = blockIdx.x >> 7;
    int h = blockIdx.x & 127;
    int tid = threadIdx.x;
    int lane = tid & 63;
    int wave = tid >> 6;
    int ph = wave & 1;
    int oh = wave >> 1;
    int l15 = lane & 15;
    int l4  = lane >> 4;

    floatx4 acc[4][2] = {};
    half8 SA[4], SB[4];     // per-slice weights: 4 half8 = 16 VGPR each

    const _Float16* wl = Wp + (size_t)oh * 18432 + lane * 8;
    const _Float16* xbase = X + ((size_t)b * PH + h) * (PH * 64);

#define LOADW1(S, k) { \
    _Pragma("unroll") \
    for (int cb = 0; cb < 2; cb++) \
      _Pragma("unroll") \
      for (int n = 0; n < 2; n++) \
        S[cb * 2 + n] = *reinterpret_cast<const half8*>( \
            wl + (size_t)((k) * 4 + cb * 2 + n) * 512); }

#define STAGE64(r) { \
    const _Float16* grow = xbase + (size_t)(r) * (PH * 64); \
    _Pragma("unroll") \
    for (int i = 0; i < 5; i++) { \
      int id = i * 256 + tid; \
      if (id < 1040) { \
        half8 v = *reinterpret_cast<const half8*>(grow + (size_t)id * 8); \
        *reinterpret_cast<half8*>(&xs[(id >> 3) * 72 + (id & 7) * 8]) = v; \
      } } }

#define COMP64(dw, S) { \
    _Pragma("unroll") \
    for (int cb = 0; cb < 2; cb++) { \
      int kofs = cb * 32 + l4 * 8; \
      half8 af[4]; \
      _Pragma("unroll") \
      for (int m = 0; m < 4; m++) { \
        int p = ph * 64 + m * 16 + l15; \
        af[m] = *reinterpret_cast<const half8*>(&xs[(p + (dw)) * 72 + kofs]); \
      } \
      _Pragma("unroll") \
      for (int m = 0; m < 4; m++) \
        _Pragma("unroll") \
        for (int n = 0; n < 2; n++) \
          acc[m][n] = __builtin_amdgcn_mfma_f32_16x16x32_f16( \
              af[m], S[cb * 2 + n], acc[m][n], 0, 0, 0); } }

    LOADW1(SA, 0);
    STAGE64(0);
    __syncthreads();
    LOADW1(SB, 1);  COMP64(0, SA);
    LOADW1(SA, 2);  COMP64(1, SB);
    LOADW1(SB, 3);  COMP64(2, SA);
    __syncthreads();
    STAGE64(1);
    __syncthreads();
    LOADW1(SA, 4);  COMP64(0, SB);
    LOADW1(SB, 5);  COMP64(1, SA);
    LOADW1(SA, 6);  COMP64(2, SB);
    __syncthreads();
    STAGE64(2);
    __syncthreads();
    LOADW1(SB, 7);  COMP64(0, SA);
    LOADW1(SA, 8);  COMP64(1, SB);
    COMP64(2, SA);

#undef LOADW1
#undef STAGE64
#undef COMP64

    _Float16* dst = Y + (((size_t)b * PH + (h + 1)) * PH + 1) * 64;
    #pragma unroll
    for (int m = 0; m < 4; m++)
        #pragma unroll
        for (int n = 0; n < 2; n++) {
            int o = oh * 32 + n * 16 + l15;
            float bv = bias[o];
            #pragma unroll
            for (int q = 0; q < 4; q++) {
                int pix = ph * 64 + m * 16 + l4 * 4 + q;
                float v = acc[m][n][q] + bv;
                v = v > 0.f ? v : 0.01f * v;
                dst[(size_t)pix * 64 + o] = (_Float16)v;
            }
        }
}

// ---------------------------------------------------------------------------
// head_fused v2: 144-out tile (= 16 WHOLE channels: 144 = 16*9) -> NO
// straddling channels, Ls/fuse_strad deleted, single dispatch over all 8
// batches. 384 thr = 6 waves (2 pxh x 3 og); og covers 48 outs = the same
// 48-out groups the WL pack already uses (g = ct*3+og). REGISTER-W ping-pong
// (r9-verified). tb [144][132] = 38016 B LDS (xs 16640 B overlays).
// grid 2048 = 2 ct x 8 b x 128 h.
// ---------------------------------------------------------------------------
__global__ __launch_bounds__(384, 2)
void head_fused(const _Float16* __restrict__ X, const _Float16* __restrict__ Wp,
                const float* __restrict__ b_last, const float* __restrict__ ms,
                const float* __restrict__ zin, float* __restrict__ out) {
    __shared__ _Float16 smem[19008];      // 38016 B: xs (16640 B) / tb overlay
    _Float16* xs = smem;                  // [130][8] half8 linear
    _Float16* tb = smem;                  // [144][132] logits (overlay)
    int blk = blockIdx.x;
    int ct = blk >> 10;         // 0..1 out-half (144 outs each)
    int b  = (blk >> 7) & 7;    // batch 0..7
    int h  = blk & 127;
    int tid = threadIdx.x;
    int lane = tid & 63;
    int wave = tid >> 6;        // 0..5
    int pxh = wave & 1;
    int og  = wave >> 1;        // 0..2 (48-out group within the 144 tile)
    int l15 = lane & 15;
    int l4  = lane >> 4;

    floatx4 acc[4][3] = {};
    half8 SA[3], SB[3];         // per-slice weights: 3 half8 = 12 VGPR each

    const _Float16* wlh = Wp + ((size_t)ct * 3 + og) * 27648 + lane * 8;
    const _Float16* xbase = X + ((size_t)b * PH + h) * (PH * 64);

#define LOADWH(S, k, cb) { \
    _Pragma("unroll") \
    for (int n = 0; n < 3; n++) \
      S[n] = *reinterpret_cast<const half8*>( \
          wlh + (size_t)(((k) * 2 + (cb)) * 3 + n) * 512); }

#define STAGEH(r) { \
    const _Float16* xrow = xbase + (size_t)(r) * (PH * 64); \
    _Pragma("unroll") \
    for (int i = 0; i < 3; i++) { \
      int sbase = i * 384 + wave * 64; \
      int s = sbase + lane; \
      if (s < 1040) { \
        int px = s >> 3; \
        int j = (s & 7) ^ (px & 7); \
        gload16(xrow + (size_t)(px * 8 + j) * 8, xs + (size_t)sbase * 8); \
      } } }

#define COMPH(dw, cb, S) { \
    int j = (cb) * 4 + l4; \
    half8 af[4]; \
    _Pragma("unroll") \
    for (int m = 0; m < 4; m++) { \
      int px = pxh * 64 + m * 16 + l15 + (dw); \
      af[m] = *reinterpret_cast<const half8*>( \
          &xs[px * 64 + (j ^ (px & 7)) * 8]); \
    } \
    _Pragma("unroll") \
    for (int m = 0; m < 4; m++) \
      _Pragma("unroll") \
      for (int n = 0; n < 3; n++) \
        acc[m][n] = __builtin_amdgcn_mfma_f32_16x16x32_f16( \
            af[m], S[n], acc[m][n], 0, 0, 0); }

    // 18 slices s = k*2+cb (k = r*3+dw); ping-pong: even->SA, odd->SB.
    LOADWH(SA, 0, 0);
    STAGEH(0);
    __syncthreads();
    LOADWH(SB, 0, 1);  COMPH(0, 0, SA);
    LOADWH(SA, 1, 0);  COMPH(0, 1, SB);
    LOADWH(SB, 1, 1);  COMPH(1, 0, SA);
    LOADWH(SA, 2, 0);  COMPH(1, 1, SB);
    LOADWH(SB, 2, 1);  COMPH(2, 0, SA);
    LOADWH(SA, 3, 0);  COMPH(2, 1, SB);
    __syncthreads();
    STAGEH(1);
    __syncthreads();
    LOADWH(SB, 3, 1);  COMPH(0, 0, SA);
    LOADWH(SA, 4, 0);  COMPH(0, 1, SB);
    LOADWH(SB, 4, 1);  COMPH(1, 0, SA);
    LOADWH(SA, 5, 0);  COMPH(1, 1, SB);
    LOADWH(SB, 5, 1);  COMPH(2, 0, SA);
    LOADWH(SA, 6, 0);  COMPH(2, 1, SB);
    __syncthreads();
    STAGEH(2);
    __syncthreads();
    LOADWH(SB, 6, 1);  COMPH(0, 0, SA);
    LOADWH(SA, 7, 0);  COMPH(0, 1, SB);
    LOADWH(SB, 7, 1);  COMPH(1, 0, SA);
    LOADWH(SA, 8, 0);  COMPH(1, 1, SB);
    LOADWH(SB, 8, 1);  COMPH(2, 0, SA);
    COMPH(2, 1, SB);

#undef LOADWH
#undef STAGEH
#undef COMPH

    __syncthreads();    // xs dead; tb overlays

    // logits (bias added) -> tb [od 0..143][132 px pitch]
    #pragma unroll
    for (int m = 0; m < 4; m++)
        #pragma unroll
        for (int n = 0; n < 3; n++) {
            int od = og * 48 + n * 16 + l15;
            float bv = b_last[ct * 144 + od];
            half4v hv;
            #pragma unroll
            for (int q = 0; q < 4; q++) hv[q] = (_Float16)(acc[m][n][q] + bv);
            *reinterpret_cast<half4v*>(&tb[od * 132 + pxh * 64 + m * 16 + l4 * 4]) = hv;
        }
    __syncthreads();

    // softmax + combine for the 16 whole channels of this half: c = ct*16+cidx,
    // logit rows cidx*9 .. cidx*9+8. 2048 px-ch over 384 threads.
    for (int i = 0; i < 6; i++) {
        int idx = i * 384 + tid;        // 0..2303
        if (idx < 2048) {
            int cidx = idx >> 7;        // 0..15
            int px = idx & 127;
            int c = ct * 16 + cidx;
            int lbase = cidx * 9;
            float L[9];
            float mx = 0.f;             // implicit zero logit
            #pragma unroll
            for (int j = 0; j < 9; j++) {
                L[j] = (float)tb[(lbase + j) * 132 + px];
                mx = fmaxf(mx, L[j]);
            }
            float ez = __expf(-mx);
            float sum = ez;
            float e[9];
            #pragma unroll
            for (int j = 0; j < 9; j++) { e[j] = __expf(L[j] - mx); sum += e[j]; }
            float inv = 1.f / sum;
            const float* msb = ms + ((size_t)b * 32 + c) * IMG;
            float accv = ez * inv * zin[((size_t)b * 32 + c) * IMG + h * HW + px];
            #pragma unroll
            for (int kh = 0; kh < 3; kh++) {
                int h2 = h + kh - 1;
                int h2c = min(max(h2, 0), 127);
                bool okh = (unsigned)h2 < 128u;
                #pragma unroll
                for (int kw = 0; kw < 3; kw++) {
                    int w2 = px + kw - 1;
                    int w2c = min(max(w2, 0), 127);
                    bool okw = (unsigned)w2 < 128u;
                    float mv = msb[h2c * HW + w2c];
                    accv += e[kh * 3 + kw] * inv * ((okh && okw) ? mv : 0.f);
                }
            }
            out[((size_t)b * 32 + c) * IMG + h * HW + px] = accv;
        }
    }
}

// ---------------------------------------------------------------------------
extern "C" void kernel_launch(void* const* d_in, const int* in_sizes, int n_in,
                              void* d_out, int out_size, void* d_ws, size_t ws_size,
                              hipStream_t stream) {
    const float* z  = (const float*)d_in[0];
    const float* bb = (const float*)d_in[1];
    const float* ms = (const float*)d_in[2];
    const float* mu = (const float*)d_in[3];
    const float* w0 = (const float*)d_in[4];
    const float* b0 = (const float*)d_in[5];
    const float* w1 = (const float*)d_in[6];
    const float* b1 = (const float*)d_in[7];
    const float* w2 = (const float*)d_in[8];
    const float* b2 = (const float*)d_in[9];
    const float* wl = (const float*)d_in[10];
    const float* bl = (const float*)d_in[11];

    char* ws = (char*)d_ws;
    _Float16* Wp0 = (_Float16*)(ws + 0);          // 184320 (fragment-ordered)
    _Float16* Wp1 = (_Float16*)(ws + 184320);     // 73728 (fragment-ordered)
    _Float16* Wp2 = (_Float16*)(ws + 258048);     // 73728 (fragment-ordered)
    _Float16* WpL = (_Float16*)(ws + 331776);     // 331776 (fragment-ordered)
    _Float16* BufA = (_Float16*)(ws + 663552);    // 43,264,000  (160ch padded)
    _Float16* BufB = (_Float16*)(ws + 43927552);  // 17,305,600  (64ch padded)

    _Float16* X0 = BufA;
    _Float16* Q1 = BufB;
    _Float16* Q2 = BufA;   // overlays X0 (dead after conv0)
    _Float16* Q3 = BufB;   // overlays Q1 (same layout -> halo stays zero)

    pack_w_all<<<(331776 + 255) / 256, 256, 0, stream>>>(w0, w1, w2, wl, Wp0, Wp1, Wp2, WpL);
    zero_pads_pre<<<(115584 + 255) / 256, 256, 0, stream>>>(X0, Q1);
    pack_in<<<1024, 256, 0, stream>>>(z, bb, ms, mu, X0);

    conv3_c160<<<1024, 256, 0, stream>>>(X0, Wp0, b0, Q1);
    zero_pads64<<<(33024 + 255) / 256, 256, 0, stream>>>(Q2);
    conv3_c64<<<1024, 256, 0, stream>>>(Q1, Wp1, b1, Q2);
    conv3_c64<<<1024, 256, 0, stream>>>(Q2, Wp2, b2, Q3);

    head_fused<<<2048, 384, 0, stream>>>(Q3, WpL, bl, ms, z, (float*)d_out);
}

// Round 13
// 161.109 us; speedup vs baseline: 1.1619x; 1.1619x over previous
//
#include <hip/hip_runtime.h>
#include <hip/hip_fp16.h>

typedef _Float16 half8 __attribute__((ext_vector_type(8)));
typedef _Float16 half4v __attribute__((ext_vector_type(4)));
typedef float floatx4 __attribute__((ext_vector_type(4)));

#define HW 128
#define IMG (HW * HW)
#define PH 130          // padded height/width
#define XP 164          // conv_c160 xs pitch (verified conflict fix, r4)

// async global->LDS, 16 B/lane: LDS dest = wave-uniform base + lane*16.
typedef __attribute__((address_space(3))) _Float16 lds_f16;
typedef __attribute__((address_space(1))) const _Float16 glb_f16;
__device__ __forceinline__ void gload16(const _Float16* g, _Float16* l) {
    __builtin_amdgcn_global_load_lds((glb_f16*)g, (lds_f16*)l, 16, 0, 0);
}

// ---------------------------------------------------------------------------
// pack all weights in ONE dispatch -- ALL layers FRAGMENT-ORDERED for direct
// register loads (r3-verified mechanism):
// w0: W0f[oh][frag=(t*5+cb)*2+n][lane][8]
// w1/w2: W1f[oh][frag=t*4+cb*2+n][lane][8]
// wl: WLf[g=of/48][frag=t*2+cb][n][lane][8]   (g = ct*2+og in head_fused)
// ---------------------------------------------------------------------------
__global__ void pack_w_all(const float* __restrict__ w0, const float* __restrict__ w1,
                           const float* __restrict__ w2, const float* __restrict__ wl,
                           _Float16* __restrict__ p0, _Float16* __restrict__ p1,
                           _Float16* __restrict__ p2, _Float16* __restrict__ pl) {
    int idx = blockIdx.x * 256 + threadIdx.x;
    if (idx < 92160) {
        int local = idx;
        int o = local / 1440;          // 160*9
        int rem = local % 1440;
        int c = rem / 9;
        int t = rem % 9;
        int oh = o >> 5, n = (o >> 4) & 1, l15 = o & 15;
        int cb = c >> 5, l4 = (c >> 3) & 3, e = c & 7;
        int frag = (t * 5 + cb) * 2 + n;
        p0[(size_t)oh * 46080 + frag * 512 + (l4 * 16 + l15) * 8 + e] =
            (_Float16)w0[local];
        return;
    }
    if (idx < 165888) {                // w1 / w2: O=64, C=64
        const float* w; _Float16* p; int local;
        if (idx < 129024) { w = w1; p = p1; local = idx - 92160; }
        else              { w = w2; p = p2; local = idx - 129024; }
        int o = local / 576;
        int rem = local % 576;
        int c = rem / 9;
        int t = rem % 9;               // t = r*3+dw
        int oh = o >> 5, n = (o >> 4) & 1, l15 = o & 15;
        int cb = c >> 5, l4 = (c >> 3) & 3, e = c & 7;
        int frag = t * 4 + cb * 2 + n; // 36 frags
        p[(size_t)oh * 18432 + frag * 512 + (l4 * 16 + l15) * 8 + e] =
            (_Float16)w[local];
        return;
    }
    if (idx < 331776) {                // wl: O=288, C=64
        int local = idx - 165888;
        int of = local / 576;
        int rem = local % 576;
        int c = rem / 9;
        int t = rem % 9;
        int g = of / 48;               // 48-out group 0..5
        int n = (of % 48) / 16;
        int l15 = of & 15;
        int j = c >> 3;                // 0..7 c-block
        int cb = j >> 2, l4 = j & 3, e = c & 7;
        int frag = t * 2 + cb;         // 18 frags
        pl[((((size_t)g * 18 + frag) * 3 + n) * 64
            + (l4 * 16 + l15)) * 8 + e] = (_Float16)wl[local];
    }
}

// ---------------------------------------------------------------------------
// zero 1-px halo of padded NHWC tensors
// ---------------------------------------------------------------------------
__device__ __forceinline__ void zero_halo(_Float16* P, int C, int id) {
    int nvec = C / 8;
    int b = id / (516 * nvec);
    int r = id % (516 * nvec);
    int cell = r / nvec;
    int v = r % nvec;
    int hh, ww;
    if (cell < 130)      { hh = 0;   ww = cell; }
    else if (cell < 260) { hh = 129; ww = cell - 130; }
    else if (cell < 388) { hh = cell - 260 + 1; ww = 0; }
    else                 { hh = cell - 388 + 1; ww = 129; }
    half8 z8 = {};
    *reinterpret_cast<half8*>(P + (((size_t)b * PH + hh) * PH + ww) * C + v * 8) = z8;
}

__global__ void zero_pads_pre(_Float16* __restrict__ X0, _Float16* __restrict__ Q1) {
    int id = blockIdx.x * 256 + threadIdx.x;     // 82560 + 33024
    if (id < 82560) zero_halo(X0, 160, id);
    else if (id < 115584) zero_halo(Q1, 64, id - 82560);
}

__global__ void zero_pads64(_Float16* __restrict__ P) {
    int id = blockIdx.x * 256 + threadIdx.x;
    if (id < 33024) zero_halo(P, 64, id);
}

// ---------------------------------------------------------------------------
// pack input -> X0 padded NHWC f16 [b][130][130][160] (interior)
// ---------------------------------------------------------------------------
__global__ __launch_bounds__(256)
void pack_in(const float* __restrict__ z, const float* __restrict__ bb,
             const float* __restrict__ ms, const float* __restrict__ mu,
             _Float16* __restrict__ X0) {
    __shared__ _Float16 lds[160 * 132];
    int b = blockIdx.x >> 7;
    int h = blockIdx.x & 127;
    int tid = threadIdx.x;

    for (int i = 0; i < 20; i++) {
        int id = i * 256 + tid;
        int c = id >> 5;
        int col = (id & 31) * 4;
        const float* src; int cs; int csz;
        if (c < 64)       { src = bb; cs = c;       csz = 64; }
        else if (c < 96)  { src = z;  cs = c - 64;  csz = 32; }
        else if (c < 128) { src = ms; cs = c - 96;  csz = 32; }
        else              { src = mu; cs = c - 128; csz = 32; }
        float4 v = *reinterpret_cast<const float4*>(
            src + ((size_t)b * csz + cs) * IMG + h * HW + col);
        half4v hv = { (_Float16)v.x, (_Float16)v.y, (_Float16)v.z, (_Float16)v.w };
        *reinterpret_cast<half4v*>(&lds[c * 132 + col]) = hv;
    }
    __syncthreads();
    _Float16* dst = X0 + (((size_t)b * PH + (h + 1)) * PH + 1) * 160;
    for (int i = 0; i < 10; i++) {
        int id = i * 256 + tid;
        int pix = id / 20;
        int c0 = (id % 20) * 8;
        half8 hv;
        #pragma unroll
        for (int e = 0; e < 8; e++) hv[e] = lds[(c0 + e) * 132 + pix];
        *reinterpret_cast<half8*>(dst + (size_t)pix * 160 + c0) = hv;
    }
}

// ---------------------------------------------------------------------------
// conv0: CIN=160. r9-verified form (~42.9 us): full-row blocks, grid 1024,
// SA/SB register weight ping-pong, fragment-ordered weights, XP=164, (256,2).
// ---------------------------------------------------------------------------
__global__ __launch_bounds__(256, 2)
void conv3_c160(const _Float16* __restrict__ X, const _Float16* __restrict__ Wp,
                const float* __restrict__ bias, _Float16* __restrict__ Y) {
    __shared__ _Float16 xs[130 * XP];   // 42640 B
    int b = blockIdx.x >> 7;
    int h = blockIdx.x & 127;
    int tid = threadIdx.x;
    int lane = tid & 63;
    int wave = tid >> 6;
    int ph = wave & 1;
    int oh = wave >> 1;
    int l15 = lane & 15;
    int l4  = lane >> 4;

    floatx4 acc[4][2] = {};
    half8 SA[10], SB[10];   // ping-pong weight slices: 10 half8 = 40 VGPR each

    const _Float16* wl = Wp + (size_t)oh * 46080 + lane * 8;

#define LOADW(S, k) { \
    _Pragma("unroll") \
    for (int cb = 0; cb < 5; cb++) \
      _Pragma("unroll") \
      for (int n = 0; n < 2; n++) \
        S[cb * 2 + n] = *reinterpret_cast<const half8*>( \
            wl + (size_t)(((k) * 5 + cb) * 2 + n) * 512); }

#define STAGE160(r) { \
    const _Float16* grow = X + ((size_t)b * PH + (h + (r))) * PH * 160; \
    _Pragma("unroll") \
    for (int i = 0; i < 11; i++) { \
      int id = i * 256 + tid; \
      if (id < 2600) { \
        half8 v = *reinterpret_cast<const half8*>(grow + (size_t)id * 8); \
        *reinterpret_cast<half8*>(&xs[(id / 20) * XP + (id % 20) * 8]) = v; \
      } } }

#define COMP160(dw, S) { \
    _Pragma("unroll") \
    for (int cb = 0; cb < 5; cb++) { \
      int kofs = cb * 32 + l4 * 8; \
      half8 af[4]; \
      _Pragma("unroll") \
      for (int m = 0; m < 4; m++) { \
        int p = ph * 64 + m * 16 + l15; \
        af[m] = *reinterpret_cast<const half8*>(&xs[(p + (dw)) * XP + kofs]); \
      } \
      _Pragma("unroll") \
      for (int m = 0; m < 4; m++) \
        _Pragma("unroll") \
        for (int n = 0; n < 2; n++) \
          acc[m][n] = __builtin_amdgcn_mfma_f32_16x16x32_f16( \
              af[m], S[cb * 2 + n], acc[m][n], 0, 0, 0); } }

    LOADW(SA, 0);
    STAGE160(0);
    __syncthreads();
    LOADW(SB, 1);  COMP160(0, SA);
    LOADW(SA, 2);  COMP160(1, SB);
    LOADW(SB, 3);  COMP160(2, SA);
    __syncthreads();
    STAGE160(1);
    __syncthreads();
    LOADW(SA, 4);  COMP160(0, SB);
    LOADW(SB, 5);  COMP160(1, SA);
    LOADW(SA, 6);  COMP160(2, SB);
    __syncthreads();
    STAGE160(2);
    __syncthreads();
    LOADW(SB, 7);  COMP160(0, SA);
    LOADW(SA, 8);  COMP160(1, SB);
    COMP160(2, SA);

#undef LOADW
#undef STAGE160
#undef COMP160

    _Float16* dst = Y + (((size_t)b * PH + (h + 1)) * PH + 1) * 64;
    #pragma unroll
    for (int m = 0; m < 4; m++)
        #pragma unroll
        for (int n = 0; n < 2; n++) {
            int o = oh * 32 + n * 16 + l15;
            float bv = bias[o];
            #pragma unroll
            for (int q = 0; q < 4; q++) {
                int pix = ph * 64 + m * 16 + l4 * 4 + q;
                float v = acc[m][n][q] + bv;
                v = v > 0.f ? v : 0.01f * v;
                dst[(size_t)pix * 64 + o] = (_Float16)v;
            }
        }
}

// ---------------------------------------------------------------------------
// conv_c64 v2 (r9-verified): REGISTER-W, no wbuf LDS. (256,2).
// ---------------------------------------------------------------------------
__global__ __launch_bounds__(256, 2)
void conv3_c64(const _Float16* __restrict__ X, const _Float16* __restrict__ Wp,
               const float* __restrict__ bias, _Float16* __restrict__ Y) {
    __shared__ _Float16 xs[130 * 72];   // 18720 B
    int b = blockIdx.x >> 7;
    int h = blockIdx.x & 127;
    int tid = threadIdx.x;
    int lane = tid & 63;
    int wave = tid >> 6;
    int ph = wave & 1;
    int oh = wave >> 1;
    int l15 = lane & 15;
    int l4  = lane >> 4;

    floatx4 acc[4][2] = {};
    half8 SA[4], SB[4];     // per-slice weights: 4 half8 = 16 VGPR each

    const _Float16* wl = Wp + (size_t)oh * 18432 + lane * 8;
    const _Float16* xbase = X + ((size_t)b * PH + h) * (PH * 64);

#define LOADW1(S, k) { \
    _Pragma("unroll") \
    for (int cb = 0; cb < 2; cb++) \
      _Pragma("unroll") \
      for (int n = 0; n < 2; n++) \
        S[cb * 2 + n] = *reinterpret_cast<const half8*>( \
            wl + (size_t)((k) * 4 + cb * 2 + n) * 512); }

#define STAGE64(r) { \
    const _Float16* grow = xbase + (size_t)(r) * (PH * 64); \
    _Pragma("unroll") \
    for (int i = 0; i < 5; i++) { \
      int id = i * 256 + tid; \
      if (id < 1040) { \
        half8 v = *reinterpret_cast<const half8*>(grow + (size_t)id * 8); \
        *reinterpret_cast<half8*>(&xs[(id >> 3) * 72 + (id & 7) * 8]) = v; \
      } } }

#define COMP64(dw, S) { \
    _Pragma("unroll") \
    for (int cb = 0; cb < 2; cb++) { \
      int kofs = cb * 32 + l4 * 8; \
      half8 af[4]; \
      _Pragma("unroll") \
      for (int m = 0; m < 4; m++) { \
        int p = ph * 64 + m * 16 + l15; \
        af[m] = *reinterpret_cast<const half8*>(&xs[(p + (dw)) * 72 + kofs]); \
      } \
      _Pragma("unroll") \
      for (int m = 0; m < 4; m++) \
        _Pragma("unroll") \
        for (int n = 0; n < 2; n++) \
          acc[m][n] = __builtin_amdgcn_mfma_f32_16x16x32_f16( \
              af[m], S[cb * 2 + n], acc[m][n], 0, 0, 0); } }

    LOADW1(SA, 0);
    STAGE64(0);
    __syncthreads();
    LOADW1(SB, 1);  COMP64(0, SA);
    LOADW1(SA, 2);  COMP64(1, SB);
    LOADW1(SB, 3);  COMP64(2, SA);
    __syncthreads();
    STAGE64(1);
    __syncthreads();
    LOADW1(SA, 4);  COMP64(0, SB);
    LOADW1(SB, 5);  COMP64(1, SA);
    LOADW1(SA, 6);  COMP64(2, SB);
    __syncthreads();
    STAGE64(2);
    __syncthreads();
    LOADW1(SB, 7);  COMP64(0, SA);
    LOADW1(SA, 8);  COMP64(1, SB);
    COMP64(2, SA);

#undef LOADW1
#undef STAGE64
#undef COMP64

    _Float16* dst = Y + (((size_t)b * PH + (h + 1)) * PH + 1) * 64;
    #pragma unroll
    for (int m = 0; m < 4; m++)
        #pragma unroll
        for (int n = 0; n < 2; n++) {
            int o = oh * 32 + n * 16 + l15;
            float bv = bias[o];
            #pragma unroll
            for (int q = 0; q < 4; q++) {
                int pix = ph * 64 + m * 16 + l4 * 4 + q;
                float v = acc[m][n][q] + bv;
                v = v > 0.f ? v : 0.01f * v;
                dst[(size_t)pix * 64 + o] = (_Float16)v;
            }
        }
}

// ---------------------------------------------------------------------------
// head_fused (r11-verified form, 96-out tile, WGS 256, (256,2)) -- single
// dispatch over ALL 8 batches: grid 3072 = 3 ct x 8 bi x 128 h. Ls sized
// for 8 batches (4.7 MB). All r11 body logic unchanged.
// ---------------------------------------------------------------------------
__global__ __launch_bounds__(256, 2)
void head_fused(const _Float16* __restrict__ X, const _Float16* __restrict__ Wp,
                const float* __restrict__ b_last, const float* __restrict__ ms,
                const float* __restrict__ zin, float* __restrict__ out,
                _Float16* __restrict__ Ls) {
    __shared__ _Float16 smem[12672];      // 25344 B: xs 8320 halfs / tb overlay
    _Float16* xs = smem;                  // [130][8] half8 linear
    _Float16* tb = smem;                  // [96][132] logits (overlay)
    int blk = blockIdx.x;
    int ct = blk >> 10;         // 0..2 out-third
    int b  = (blk >> 7) & 7;    // batch 0..7
    int h  = blk & 127;
    int tid = threadIdx.x;
    int lane = tid & 63;
    int wave = tid >> 6;
    int pxh = wave & 1;
    int og  = wave >> 1;        // 0..1
    int l15 = lane & 15;
    int l4  = lane >> 4;

    floatx4 acc[4][3] = {};
    half8 SA[3], SB[3];         // per-slice weights: 3 half8 = 12 VGPR each

    const _Float16* wlh = Wp + ((size_t)ct * 2 + og) * 27648 + lane * 8;
    const _Float16* xbase = X + ((size_t)b * PH + h) * (PH * 64);

#define LOADWH(S, k, cb) { \
    _Pragma("unroll") \
    for (int n = 0; n < 3; n++) \
      S[n] = *reinterpret_cast<const half8*>( \
          wlh + (size_t)(((k) * 2 + (cb)) * 3 + n) * 512); }

#define STAGEH(r) { \
    const _Float16* xrow = xbase + (size_t)(r) * (PH * 64); \
    _Pragma("unroll") \
    for (int i = 0; i < 5; i++) { \
      int sbase = i * 256 + wave * 64; \
      int s = sbase + lane; \
      if (s < 1040) { \
        int px = s >> 3; \
        int j = (s & 7) ^ (px & 7); \
        gload16(xrow + (size_t)(px * 8 + j) * 8, xs + (size_t)sbase * 8); \
      } } }

#define COMPH(dw, cb, S) { \
    int j = (cb) * 4 + l4; \
    half8 af[4]; \
    _Pragma("unroll") \
    for (int m = 0; m < 4; m++) { \
      int px = pxh * 64 + m * 16 + l15 + (dw); \
      af[m] = *reinterpret_cast<const half8*>( \
          &xs[px * 64 + (j ^ (px & 7)) * 8]); \
    } \
    _Pragma("unroll") \
    for (int m = 0; m < 4; m++) \
      _Pragma("unroll") \
      for (int n = 0; n < 3; n++) \
        acc[m][n] = __builtin_amdgcn_mfma_f32_16x16x32_f16( \
            af[m], S[n], acc[m][n], 0, 0, 0); }

    // 18 slices s = k*2+cb (k = r*3+dw); ping-pong: even->SA, odd->SB.
    LOADWH(SA, 0, 0);
    STAGEH(0);
    __syncthreads();
    LOADWH(SB, 0, 1);  COMPH(0, 0, SA);
    LOADWH(SA, 1, 0);  COMPH(0, 1, SB);
    LOADWH(SB, 1, 1);  COMPH(1, 0, SA);
    LOADWH(SA, 2, 0);  COMPH(1, 1, SB);
    LOADWH(SB, 2, 1);  COMPH(2, 0, SA);
    LOADWH(SA, 3, 0);  COMPH(2, 1, SB);
    __syncthreads();
    STAGEH(1);
    __syncthreads();
    LOADWH(SB, 3, 1);  COMPH(0, 0, SA);
    LOADWH(SA, 4, 0);  COMPH(0, 1, SB);
    LOADWH(SB, 4, 1);  COMPH(1, 0, SA);
    LOADWH(SA, 5, 0);  COMPH(1, 1, SB);
    LOADWH(SB, 5, 1);  COMPH(2, 0, SA);
    LOADWH(SA, 6, 0);  COMPH(2, 1, SB);
    __syncthreads();
    STAGEH(2);
    __syncthreads();
    LOADWH(SB, 6, 1);  COMPH(0, 0, SA);
    LOADWH(SA, 7, 0);  COMPH(0, 1, SB);
    LOADWH(SB, 7, 1);  COMPH(1, 0, SA);
    LOADWH(SA, 8, 0);  COMPH(1, 1, SB);
    LOADWH(SB, 8, 1);  COMPH(2, 0, SA);
    COMPH(2, 1, SB);

#undef LOADWH
#undef STAGEH
#undef COMPH

    __syncthreads();    // xs dead; tb overlays

    // logits (bias added) -> tb [od 0..95][132 px pitch]
    #pragma unroll
    for (int m = 0; m < 4; m++)
        #pragma unroll
        for (int n = 0; n < 3; n++) {
            int od = og * 48 + n * 16 + l15;
            float bv = b_last[ct * 96 + od];
            half4v hv;
            #pragma unroll
            for (int q = 0; q < 4; q++) hv[q] = (_Float16)(acc[m][n][q] + bv);
            *reinterpret_cast<half4v*>(&tb[od * 132 + pxh * 64 + m * 16 + l4 * 4]) = hv;
        }
    __syncthreads();

    // (a) straddle logit rows -> Ls (6 rows x 128 px = 96 half8 writes)
    if (tid < 96) {
        int rowi = tid >> 4;        // 0..5
        int sl = tid & 15;
        int localrow, slot;
        if (ct == 0)      { localrow = 90 + rowi; slot = rowi; }       // c10 j0-5
        else if (ct == 1) { localrow = (rowi < 3) ? rowi : 90 + rowi;  // c10 j6-8,
                            slot = 6 + rowi; }                          // c21 j0-2
        else              { localrow = rowi; slot = 12 + rowi; }       // c21 j3-8
        half8 v = *reinterpret_cast<const half8*>(&tb[localrow * 132 + sl * 8]);
        *reinterpret_cast<half8*>(
            Ls + (((size_t)(b * 128 + h) * 18 + slot) * 128 + sl * 8)) = v;
    }

    // (b) interior channels: softmax + combine, write out directly.
    // ct0: c=0..9; ct1: c=11..20; ct2: c=22..31. lbase = c*9 - ct*96.
    #pragma unroll
    for (int i = 0; i < 5; i++) {
        int idx = i * 256 + tid;        // 0..1279
        int cidx = idx >> 7;            // 0..9
        int px = idx & 127;
        int c = (ct == 0) ? cidx : ((ct == 1) ? 11 + cidx : 22 + cidx);
        int lbase = c * 9 - ct * 96;
        float L[9];
        float mx = 0.f;                 // implicit zero logit
        #pragma unroll
        for (int j = 0; j < 9; j++) {
            L[j] = (float)tb[(lbase + j) * 132 + px];
            mx = fmaxf(mx, L[j]);
        }
        float ez = __expf(-mx);
        float sum = ez;
        float e[9];
        #pragma unroll
        for (int j = 0; j < 9; j++) { e[j] = __expf(L[j] - mx); sum += e[j]; }
        float inv = 1.f / sum;
        const float* msb = ms + ((size_t)b * 32 + c) * IMG;
        float accv = ez * inv * zin[((size_t)b * 32 + c) * IMG + h * HW + px];
        #pragma unroll
        for (int kh = 0; kh < 3; kh++) {
            int h2 = h + kh - 1;
            int h2c = min(max(h2, 0), 127);
            bool okh = (unsigned)h2 < 128u;
            #pragma unroll
            for (int kw = 0; kw < 3; kw++) {
                int w2 = px + kw - 1;
                int w2c = min(max(w2, 0), 127);
                bool okw = (unsigned)w2 < 128u;
                float mv = msb[h2c * HW + w2c];
                accv += e[kh * 3 + kw] * inv * ((okh && okw) ? mv : 0.f);
            }
        }
        out[((size_t)b * 32 + c) * IMG + h * HW + px] = accv;
    }
}

// ---------------------------------------------------------------------------
// fuse_strad: cleanup for the 2 straddling channels (c10, c21), all 8
// batches in one dispatch. grid 1024 (b x h), 256 thr = 2 ch x 128 px.
// ---------------------------------------------------------------------------
__global__ __launch_bounds__(256)
void fuse_strad(const _Float16* __restrict__ Ls, const float* __restrict__ ms,
                const float* __restrict__ zin, float* __restrict__ out) {
    int blk = blockIdx.x;
    int b = blk >> 7;
    int h = blk & 127;
    int tid = threadIdx.x;
    int cs = tid >> 7;              // 0 -> c10, 1 -> c21
    int px = tid & 127;
    int c = cs ? 21 : 10;
    int sb = cs ? 9 : 0;

    const _Float16* lrow = Ls + (((size_t)(b * 128 + h) * 18 + sb) * 128) + px;
    float L[9];
    float mx = 0.f;                 // implicit zero logit
    #pragma unroll
    for (int j = 0; j < 9; j++) { L[j] = (float)lrow[j * 128]; mx = fmaxf(mx, L[j]); }
    float ez = __expf(-mx);
    float sum = ez;
    float e[9];
    #pragma unroll
    for (int j = 0; j < 9; j++) { e[j] = __expf(L[j] - mx); sum += e[j]; }
    float inv = 1.f / sum;
    const float* msb = ms + ((size_t)b * 32 + c) * IMG;
    float accv = ez * inv * zin[((size_t)b * 32 + c) * IMG + h * HW + px];
    #pragma unroll
    for (int kh = 0; kh < 3; kh++) {
        int h2 = h + kh - 1;
        int h2c = min(max(h2, 0), 127);
        bool okh = (unsigned)h2 < 128u;
        #pragma unroll
        for (int kw = 0; kw < 3; kw++) {
            int w2 = px + kw - 1;
            int w2c = min(max(w2, 0), 127);
            bool okw = (unsigned)w2 < 128u;
            float mv = msb[h2c * HW + w2c];
            accv += e[kh * 3 + kw] * inv * ((okh && okw) ? mv : 0.f);
        }
    }
    out[((size_t)b * 32 + c) * IMG + h * HW + px] = accv;
}

// ---------------------------------------------------------------------------
extern "C" void kernel_launch(void* const* d_in, const int* in_sizes, int n_in,
                              void* d_out, int out_size, void* d_ws, size_t ws_size,
                              hipStream_t stream) {
    const float* z  = (const float*)d_in[0];
    const float* bb = (const float*)d_in[1];
    const float* ms = (const float*)d_in[2];
    const float* mu = (const float*)d_in[3];
    const float* w0 = (const float*)d_in[4];
    const float* b0 = (const float*)d_in[5];
    const float* w1 = (const float*)d_in[6];
    const float* b1 = (const float*)d_in[7];
    const float* w2 = (const float*)d_in[8];
    const float* b2 = (const float*)d_in[9];
    const float* wl = (const float*)d_in[10];
    const float* bl = (const float*)d_in[11];

    char* ws = (char*)d_ws;
    _Float16* Wp0 = (_Float16*)(ws + 0);          // 184320 (fragment-ordered)
    _Float16* Wp1 = (_Float16*)(ws + 184320);     // 73728 (fragment-ordered)
    _Float16* Wp2 = (_Float16*)(ws + 258048);     // 73728 (fragment-ordered)
    _Float16* WpL = (_Float16*)(ws + 331776);     // 331776 (fragment-ordered)
    _Float16* BufA = (_Float16*)(ws + 663552);    // 43,264,000  (160ch padded)
    _Float16* BufB = (_Float16*)(ws + 43927552);  // 17,305,600  (64ch padded)

    _Float16* X0 = BufA;
    _Float16* Q1 = BufB;
    _Float16* Q2 = BufA;   // overlays X0 (dead after conv0)
    _Float16* Q3 = BufB;   // overlays Q1 (same layout -> halo stays zero)
    _Float16* Ls = BufA;   // straddle-logit buffer, 8 batches = 4.7 MB

    pack_w_all<<<(331776 + 255) / 256, 256, 0, stream>>>(w0, w1, w2, wl, Wp0, Wp1, Wp2, WpL);
    zero_pads_pre<<<(115584 + 255) / 256, 256, 0, stream>>>(X0, Q1);
    pack_in<<<1024, 256, 0, stream>>>(z, bb, ms, mu, X0);

    conv3_c160<<<1024, 256, 0, stream>>>(X0, Wp0, b0, Q1);
    zero_pads64<<<(33024 + 255) / 256, 256, 0, stream>>>(Q2);
    conv3_c64<<<1024, 256, 0, stream>>>(Q1, Wp1, b1, Q2);
    conv3_c64<<<1024, 256, 0, stream>>>(Q2, Wp2, b2, Q3);

    head_fused<<<3072, 256, 0, stream>>>(Q3, WpL, bl, ms, z, (float*)d_out, Ls);
    fuse_strad<<<1024, 256, 0, stream>>>(Ls, ms, z, (float*)d_out);
}

// Round 14
// 157.856 us; speedup vs baseline: 1.1859x; 1.0206x over previous
//
#include <hip/hip_runtime.h>
#include <hip/hip_fp16.h>

typedef _Float16 half8 __attribute__((ext_vector_type(8)));
typedef _Float16 half4v __attribute__((ext_vector_type(4)));
typedef float floatx4 __attribute__((ext_vector_type(4)));

#define HW 128
#define IMG (HW * HW)
#define PH 130          // padded height/width
#define XP 164          // conv_c160 xs pitch (verified conflict fix, r4)

// async global->LDS, 16 B/lane: LDS dest = wave-uniform base + lane*16.
typedef __attribute__((address_space(3))) _Float16 lds_f16;
typedef __attribute__((address_space(1))) const _Float16 glb_f16;
__device__ __forceinline__ void gload16(const _Float16* g, _Float16* l) {
    __builtin_amdgcn_global_load_lds((glb_f16*)g, (lds_f16*)l, 16, 0, 0);
}

// ---------------------------------------------------------------------------
// pack all weights in ONE dispatch -- ALL layers FRAGMENT-ORDERED for direct
// register loads (r3-verified mechanism):
// w0: W0f[oh][frag=(t*5+cb)*2+n][lane][8]
// w1/w2: W1f[oh][frag=t*4+cb*2+n][lane][8]
// wl: WLf[g=of/48][frag=t*2+cb][n][lane][8]   (g = ct*2+og in head_fused)
// ---------------------------------------------------------------------------
__global__ void pack_w_all(const float* __restrict__ w0, const float* __restrict__ w1,
                           const float* __restrict__ w2, const float* __restrict__ wl,
                           _Float16* __restrict__ p0, _Float16* __restrict__ p1,
                           _Float16* __restrict__ p2, _Float16* __restrict__ pl) {
    int idx = blockIdx.x * 256 + threadIdx.x;
    if (idx < 92160) {
        int local = idx;
        int o = local / 1440;          // 160*9
        int rem = local % 1440;
        int c = rem / 9;
        int t = rem % 9;
        int oh = o >> 5, n = (o >> 4) & 1, l15 = o & 15;
        int cb = c >> 5, l4 = (c >> 3) & 3, e = c & 7;
        int frag = (t * 5 + cb) * 2 + n;
        p0[(size_t)oh * 46080 + frag * 512 + (l4 * 16 + l15) * 8 + e] =
            (_Float16)w0[local];
        return;
    }
    if (idx < 165888) {                // w1 / w2: O=64, C=64
        const float* w; _Float16* p; int local;
        if (idx < 129024) { w = w1; p = p1; local = idx - 92160; }
        else              { w = w2; p = p2; local = idx - 129024; }
        int o = local / 576;
        int rem = local % 576;
        int c = rem / 9;
        int t = rem % 9;               // t = r*3+dw
        int oh = o >> 5, n = (o >> 4) & 1, l15 = o & 15;
        int cb = c >> 5, l4 = (c >> 3) & 3, e = c & 7;
        int frag = t * 4 + cb * 2 + n; // 36 frags
        p[(size_t)oh * 18432 + frag * 512 + (l4 * 16 + l15) * 8 + e] =
            (_Float16)w[local];
        return;
    }
    if (idx < 331776) {                // wl: O=288, C=64
        int local = idx - 165888;
        int of = local / 576;
        int rem = local % 576;
        int c = rem / 9;
        int t = rem % 9;
        int g = of / 48;               // 48-out group 0..5
        int n = (of % 48) / 16;
        int l15 = of & 15;
        int j = c >> 3;                // 0..7 c-block
        int cb = j >> 2, l4 = j & 3, e = c & 7;
        int frag = t * 2 + cb;         // 18 frags
        pl[((((size_t)g * 18 + frag) * 3 + n) * 64
            + (l4 * 16 + l15)) * 8 + e] = (_Float16)wl[local];
    }
}

// ---------------------------------------------------------------------------
// pack input -> X0 padded NHWC f16 [b][130][130][160] (interior) + X0 halo
// zeroing folded in (zero_pads_pre deleted): each block zeroes cols 0/129 of
// its own padded row; blocks h==0 / h==127 also zero padded rows 0 / 129.
// ---------------------------------------------------------------------------
__global__ __launch_bounds__(256)
void pack_in(const float* __restrict__ z, const float* __restrict__ bb,
             const float* __restrict__ ms, const float* __restrict__ mu,
             _Float16* __restrict__ X0) {
    __shared__ _Float16 lds[160 * 132];
    int b = blockIdx.x >> 7;
    int h = blockIdx.x & 127;
    int tid = threadIdx.x;

    for (int i = 0; i < 20; i++) {
        int id = i * 256 + tid;
        int c = id >> 5;
        int col = (id & 31) * 4;
        const float* src; int cs; int csz;
        if (c < 64)       { src = bb; cs = c;       csz = 64; }
        else if (c < 96)  { src = z;  cs = c - 64;  csz = 32; }
        else if (c < 128) { src = ms; cs = c - 96;  csz = 32; }
        else              { src = mu; cs = c - 128; csz = 32; }
        float4 v = *reinterpret_cast<const float4*>(
            src + ((size_t)b * csz + cs) * IMG + h * HW + col);
        half4v hv = { (_Float16)v.x, (_Float16)v.y, (_Float16)v.z, (_Float16)v.w };
        *reinterpret_cast<half4v*>(&lds[c * 132 + col]) = hv;
    }
    __syncthreads();
    _Float16* dst = X0 + (((size_t)b * PH + (h + 1)) * PH + 1) * 160;
    for (int i = 0; i < 10; i++) {
        int id = i * 256 + tid;
        int pix = id / 20;
        int c0 = (id % 20) * 8;
        half8 hv;
        #pragma unroll
        for (int e = 0; e < 8; e++) hv[e] = lds[(c0 + e) * 132 + pix];
        *reinterpret_cast<half8*>(dst + (size_t)pix * 160 + c0) = hv;
    }

    // ---- folded halo zeroing ----
    half8 z8 = {};
    _Float16* rowp = X0 + (((size_t)b * PH + (h + 1)) * PH) * 160;
    if (tid < 40) {                       // cols 0 and 129 of this row
        int col = (tid < 20) ? 0 : 129;
        int v = (tid < 20) ? tid : tid - 20;
        *reinterpret_cast<half8*>(rowp + (size_t)col * 160 + v * 8) = z8;
    }
    if (h == 0 || h == 127) {             // padded rows 0 / 129, full width
        int prow = (h == 0) ? 0 : 129;
        _Float16* rp = X0 + (((size_t)b * PH + prow) * PH) * 160;
        for (int i = tid; i < 2600; i += 256)
            *reinterpret_cast<half8*>(rp + (size_t)i * 8) = z8;
    }
}

// ---------------------------------------------------------------------------
// conv0: CIN=160. r9-verified form (~42.9 us): full-row blocks, grid 1024,
// SA/SB register weight ping-pong, fragment-ordered weights, XP=164, (256,2).
// + Q1 halo zeroing folded into the epilogue (zero_pads_pre deleted).
// ---------------------------------------------------------------------------
__global__ __launch_bounds__(256, 2)
void conv3_c160(const _Float16* __restrict__ X, const _Float16* __restrict__ Wp,
                const float* __restrict__ bias, _Float16* __restrict__ Y) {
    __shared__ _Float16 xs[130 * XP];   // 42640 B
    int b = blockIdx.x >> 7;
    int h = blockIdx.x & 127;
    int tid = threadIdx.x;
    int lane = tid & 63;
    int wave = tid >> 6;
    int ph = wave & 1;
    int oh = wave >> 1;
    int l15 = lane & 15;
    int l4  = lane >> 4;

    floatx4 acc[4][2] = {};
    half8 SA[10], SB[10];   // ping-pong weight slices: 10 half8 = 40 VGPR each

    const _Float16* wl = Wp + (size_t)oh * 46080 + lane * 8;

#define LOADW(S, k) { \
    _Pragma("unroll") \
    for (int cb = 0; cb < 5; cb++) \
      _Pragma("unroll") \
      for (int n = 0; n < 2; n++) \
        S[cb * 2 + n] = *reinterpret_cast<const half8*>( \
            wl + (size_t)(((k) * 5 + cb) * 2 + n) * 512); }

#define STAGE160(r) { \
    const _Float16* grow = X + ((size_t)b * PH + (h + (r))) * PH * 160; \
    _Pragma("unroll") \
    for (int i = 0; i < 11; i++) { \
      int id = i * 256 + tid; \
      if (id < 2600) { \
        half8 v = *reinterpret_cast<const half8*>(grow + (size_t)id * 8); \
        *reinterpret_cast<half8*>(&xs[(id / 20) * XP + (id % 20) * 8]) = v; \
      } } }

#define COMP160(dw, S) { \
    _Pragma("unroll") \
    for (int cb = 0; cb < 5; cb++) { \
      int kofs = cb * 32 + l4 * 8; \
      half8 af[4]; \
      _Pragma("unroll") \
      for (int m = 0; m < 4; m++) { \
        int p = ph * 64 + m * 16 + l15; \
        af[m] = *reinterpret_cast<const half8*>(&xs[(p + (dw)) * XP + kofs]); \
      } \
      _Pragma("unroll") \
      for (int m = 0; m < 4; m++) \
        _Pragma("unroll") \
        for (int n = 0; n < 2; n++) \
          acc[m][n] = __builtin_amdgcn_mfma_f32_16x16x32_f16( \
              af[m], S[cb * 2 + n], acc[m][n], 0, 0, 0); } }

    LOADW(SA, 0);
    STAGE160(0);
    __syncthreads();
    LOADW(SB, 1);  COMP160(0, SA);
    LOADW(SA, 2);  COMP160(1, SB);
    LOADW(SB, 3);  COMP160(2, SA);
    __syncthreads();
    STAGE160(1);
    __syncthreads();
    LOADW(SA, 4);  COMP160(0, SB);
    LOADW(SB, 5);  COMP160(1, SA);
    LOADW(SA, 6);  COMP160(2, SB);
    __syncthreads();
    STAGE160(2);
    __syncthreads();
    LOADW(SB, 7);  COMP160(0, SA);
    LOADW(SA, 8);  COMP160(1, SB);
    COMP160(2, SA);

#undef LOADW
#undef STAGE160
#undef COMP160

    _Float16* dst = Y + (((size_t)b * PH + (h + 1)) * PH + 1) * 64;
    #pragma unroll
    for (int m = 0; m < 4; m++)
        #pragma unroll
        for (int n = 0; n < 2; n++) {
            int o = oh * 32 + n * 16 + l15;
            float bv = bias[o];
            #pragma unroll
            for (int q = 0; q < 4; q++) {
                int pix = ph * 64 + m * 16 + l4 * 4 + q;
                float v = acc[m][n][q] + bv;
                v = v > 0.f ? v : 0.01f * v;
                dst[(size_t)pix * 64 + o] = (_Float16)v;
            }
        }

    // ---- folded Q1 halo zeroing ----
    half8 z8 = {};
    _Float16* rowq = Y + (((size_t)b * PH + (h + 1)) * PH) * 64;
    if (tid < 16) {                       // cols 0 and 129 of this row
        int col = (tid < 8) ? 0 : 129;
        int v = tid & 7;
        *reinterpret_cast<half8*>(rowq + (size_t)col * 64 + v * 8) = z8;
    }
    if (h == 0 || h == 127) {             // padded rows 0 / 129
        int prow = (h == 0) ? 0 : 129;
        _Float16* rp = Y + (((size_t)b * PH + prow) * PH) * 64;
        for (int i = tid; i < 1040; i += 256)
            *reinterpret_cast<half8*>(rp + (size_t)i * 8) = z8;
    }
}

// ---------------------------------------------------------------------------
// conv_c64 v2 (r9-verified): REGISTER-W, no wbuf LDS. (256,2).
// + output halo zeroing folded in (zero_pads64 deleted). Unconditional:
// call#1 zeroes Q2's halo (required -- Q2 overlays dead X0 garbage);
// call#2 re-zeroes Q3's halo (idempotent, already zero).
// ---------------------------------------------------------------------------
__global__ __launch_bounds__(256, 2)
void conv3_c64(const _Float16* __restrict__ X, const _Float16* __restrict__ Wp,
               const float* __restrict__ bias, _Float16* __restrict__ Y) {
    __shared__ _Float16 xs[130 * 72];   // 18720 B
    int b = blockIdx.x >> 7;
    int h = blockIdx.x & 127;
    int tid = threadIdx.x;
    int lane = tid & 63;
    int wave = tid >> 6;
    int ph = wave & 1;
    int oh = wave >> 1;
    int l15 = lane & 15;
    int l4  = lane >> 4;

    floatx4 acc[4][2] = {};
    half8 SA[4], SB[4];     // per-slice weights: 4 half8 = 16 VGPR each

    const _Float16* wl = Wp + (size_t)oh * 18432 + lane * 8;
    const _Float16* xbase = X + ((size_t)b * PH + h) * (PH * 64);

#define LOADW1(S, k) { \
    _Pragma("unroll") \
    for (int cb = 0; cb < 2; cb++) \
      _Pragma("unroll") \
      for (int n = 0; n < 2; n++) \
        S[cb * 2 + n] = *reinterpret_cast<const half8*>( \
            wl + (size_t)((k) * 4 + cb * 2 + n) * 512); }

#define STAGE64(r) { \
    const _Float16* grow = xbase + (size_t)(r) * (PH * 64); \
    _Pragma("unroll") \
    for (int i = 0; i < 5; i++) { \
      int id = i * 256 + tid; \
      if (id < 1040) { \
        half8 v = *reinterpret_cast<const half8*>(grow + (size_t)id * 8); \
        *reinterpret_cast<half8*>(&xs[(id >> 3) * 72 + (id & 7) * 8]) = v; \
      } } }

#define COMP64(dw, S) { \
    _Pragma("unroll") \
    for (int cb = 0; cb < 2; cb++) { \
      int kofs = cb * 32 + l4 * 8; \
      half8 af[4]; \
      _Pragma("unroll") \
      for (int m = 0; m < 4; m++) { \
        int p = ph * 64 + m * 16 + l15; \
        af[m] = *reinterpret_cast<const half8*>(&xs[(p + (dw)) * 72 + kofs]); \
      } \
      _Pragma("unroll") \
      for (int m = 0; m < 4; m++) \
        _Pragma("unroll") \
        for (int n = 0; n < 2; n++) \
          acc[m][n] = __builtin_amdgcn_mfma_f32_16x16x32_f16( \
              af[m], S[cb * 2 + n], acc[m][n], 0, 0, 0); } }

    LOADW1(SA, 0);
    STAGE64(0);
    __syncthreads();
    LOADW1(SB, 1);  COMP64(0, SA);
    LOADW1(SA, 2);  COMP64(1, SB);
    LOADW1(SB, 3);  COMP64(2, SA);
    __syncthreads();
    STAGE64(1);
    __syncthreads();
    LOADW1(SA, 4);  COMP64(0, SB);
    LOADW1(SB, 5);  COMP64(1, SA);
    LOADW1(SA, 6);  COMP64(2, SB);
    __syncthreads();
    STAGE64(2);
    __syncthreads();
    LOADW1(SB, 7);  COMP64(0, SA);
    LOADW1(SA, 8);  COMP64(1, SB);
    COMP64(2, SA);

#undef LOADW1
#undef STAGE64
#undef COMP64

    _Float16* dst = Y + (((size_t)b * PH + (h + 1)) * PH + 1) * 64;
    #pragma unroll
    for (int m = 0; m < 4; m++)
        #pragma unroll
        for (int n = 0; n < 2; n++) {
            int o = oh * 32 + n * 16 + l15;
            float bv = bias[o];
            #pragma unroll
            for (int q = 0; q < 4; q++) {
                int pix = ph * 64 + m * 16 + l4 * 4 + q;
                float v = acc[m][n][q] + bv;
                v = v > 0.f ? v : 0.01f * v;
                dst[(size_t)pix * 64 + o] = (_Float16)v;
            }
        }

    // ---- folded output halo zeroing ----
    half8 z8 = {};
    _Float16* rowq = Y + (((size_t)b * PH + (h + 1)) * PH) * 64;
    if (tid < 16) {                       // cols 0 and 129 of this row
        int col = (tid < 8) ? 0 : 129;
        int v = tid & 7;
        *reinterpret_cast<half8*>(rowq + (size_t)col * 64 + v * 8) = z8;
    }
    if (h == 0 || h == 127) {             // padded rows 0 / 129
        int prow = (h == 0) ? 0 : 129;
        _Float16* rp = Y + (((size_t)b * PH + prow) * PH) * 64;
        for (int i = tid; i < 1040; i += 256)
            *reinterpret_cast<half8*>(rp + (size_t)i * 8) = z8;
    }
}

// ---------------------------------------------------------------------------
// head_fused (r13-verified, 58.4 us): 96-out tile, WGS 256, (256,2), single
// dispatch over all 8 batches (grid 3072 = 3 ct x 8 b x 128 h). Register-W
// ping-pong GEMM -> logits in LDS tb -> fused softmax/combine for the 30
// interior channels; 6 straddle logit rows exported to compact Ls.
// ---------------------------------------------------------------------------
__global__ __launch_bounds__(256, 2)
void head_fused(const _Float16* __restrict__ X, const _Float16* __restrict__ Wp,
                const float* __restrict__ b_last, const float* __restrict__ ms,
                const float* __restrict__ zin, float* __restrict__ out,
                _Float16* __restrict__ Ls) {
    __shared__ _Float16 smem[12672];      // 25344 B: xs 8320 halfs / tb overlay
    _Float16* xs = smem;                  // [130][8] half8 linear
    _Float16* tb = smem;                  // [96][132] logits (overlay)
    int blk = blockIdx.x;
    int ct = blk >> 10;         // 0..2 out-third
    int b  = (blk >> 7) & 7;    // batch 0..7
    int h  = blk & 127;
    int tid = threadIdx.x;
    int lane = tid & 63;
    int wave = tid >> 6;
    int pxh = wave & 1;
    int og  = wave >> 1;        // 0..1
    int l15 = lane & 15;
    int l4  = lane >> 4;

    floatx4 acc[4][3] = {};
    half8 SA[3], SB[3];         // per-slice weights: 3 half8 = 12 VGPR each

    const _Float16* wlh = Wp + ((size_t)ct * 2 + og) * 27648 + lane * 8;
    const _Float16* xbase = X + ((size_t)b * PH + h) * (PH * 64);

#define LOADWH(S, k, cb) { \
    _Pragma("unroll") \
    for (int n = 0; n < 3; n++) \
      S[n] = *reinterpret_cast<const half8*>( \
          wlh + (size_t)(((k) * 2 + (cb)) * 3 + n) * 512); }

#define STAGEH(r) { \
    const _Float16* xrow = xbase + (size_t)(r) * (PH * 64); \
    _Pragma("unroll") \
    for (int i = 0; i < 5; i++) { \
      int sbase = i * 256 + wave * 64; \
      int s = sbase + lane; \
      if (s < 1040) { \
        int px = s >> 3; \
        int j = (s & 7) ^ (px & 7); \
        gload16(xrow + (size_t)(px * 8 + j) * 8, xs + (size_t)sbase * 8); \
      } } }

#define COMPH(dw, cb, S) { \
    int j = (cb) * 4 + l4; \
    half8 af[4]; \
    _Pragma("unroll") \
    for (int m = 0; m < 4; m++) { \
      int px = pxh * 64 + m * 16 + l15 + (dw); \
      af[m] = *reinterpret_cast<const half8*>( \
          &xs[px * 64 + (j ^ (px & 7)) * 8]); \
    } \
    _Pragma("unroll") \
    for (int m = 0; m < 4; m++) \
      _Pragma("unroll") \
      for (int n = 0; n < 3; n++) \
        acc[m][n] = __builtin_amdgcn_mfma_f32_16x16x32_f16( \
            af[m], S[n], acc[m][n], 0, 0, 0); }

    // 18 slices s = k*2+cb (k = r*3+dw); ping-pong: even->SA, odd->SB.
    LOADWH(SA, 0, 0);
    STAGEH(0);
    __syncthreads();
    LOADWH(SB, 0, 1);  COMPH(0, 0, SA);
    LOADWH(SA, 1, 0);  COMPH(0, 1, SB);
    LOADWH(SB, 1, 1);  COMPH(1, 0, SA);
    LOADWH(SA, 2, 0);  COMPH(1, 1, SB);
    LOADWH(SB, 2, 1);  COMPH(2, 0, SA);
    LOADWH(SA, 3, 0);  COMPH(2, 1, SB);
    __syncthreads();
    STAGEH(1);
    __syncthreads();
    LOADWH(SB, 3, 1);  COMPH(0, 0, SA);
    LOADWH(SA, 4, 0);  COMPH(0, 1, SB);
    LOADWH(SB, 4, 1);  COMPH(1, 0, SA);
    LOADWH(SA, 5, 0);  COMPH(1, 1, SB);
    LOADWH(SB, 5, 1);  COMPH(2, 0, SA);
    LOADWH(SA, 6, 0);  COMPH(2, 1, SB);
    __syncthreads();
    STAGEH(2);
    __syncthreads();
    LOADWH(SB, 6, 1);  COMPH(0, 0, SA);
    LOADWH(SA, 7, 0);  COMPH(0, 1, SB);
    LOADWH(SB, 7, 1);  COMPH(1, 0, SA);
    LOADWH(SA, 8, 0);  COMPH(1, 1, SB);
    LOADWH(SB, 8, 1);  COMPH(2, 0, SA);
    COMPH(2, 1, SB);

#undef LOADWH
#undef STAGEH
#undef COMPH

    __syncthreads();    // xs dead; tb overlays

    // logits (bias added) -> tb [od 0..95][132 px pitch]
    #pragma unroll
    for (int m = 0; m < 4; m++)
        #pragma unroll
        for (int n = 0; n < 3; n++) {
            int od = og * 48 + n * 16 + l15;
            float bv = b_last[ct * 96 + od];
            half4v hv;
            #pragma unroll
            for (int q = 0; q < 4; q++) hv[q] = (_Float16)(acc[m][n][q] + bv);
            *reinterpret_cast<half4v*>(&tb[od * 132 + pxh * 64 + m * 16 + l4 * 4]) = hv;
        }
    __syncthreads();

    // (a) straddle logit rows -> Ls (6 rows x 128 px = 96 half8 writes)
    if (tid < 96) {
        int rowi = tid >> 4;        // 0..5
        int sl = tid & 15;
        int localrow, slot;
        if (ct == 0)      { localrow = 90 + rowi; slot = rowi; }       // c10 j0-5
        else if (ct == 1) { localrow = (rowi < 3) ? rowi : 90 + rowi;  // c10 j6-8,
                            slot = 6 + rowi; }                          // c21 j0-2
        else              { localrow = rowi; slot = 12 + rowi; }       // c21 j3-8
        half8 v = *reinterpret_cast<const half8*>(&tb[localrow * 132 + sl * 8]);
        *reinterpret_cast<half8*>(
            Ls + (((size_t)(b * 128 + h) * 18 + slot) * 128 + sl * 8)) = v;
    }

    // (b) interior channels: softmax + combine, write out directly.
    // ct0: c=0..9; ct1: c=11..20; ct2: c=22..31. lbase = c*9 - ct*96.
    #pragma unroll
    for (int i = 0; i < 5; i++) {
        int idx = i * 256 + tid;        // 0..1279
        int cidx = idx >> 7;            // 0..9
        int px = idx & 127;
        int c = (ct == 0) ? cidx : ((ct == 1) ? 11 + cidx : 22 + cidx);
        int lbase = c * 9 - ct * 96;
        float L[9];
        float mx = 0.f;                 // implicit zero logit
        #pragma unroll
        for (int j = 0; j < 9; j++) {
            L[j] = (float)tb[(lbase + j) * 132 + px];
            mx = fmaxf(mx, L[j]);
        }
        float ez = __expf(-mx);
        float sum = ez;
        float e[9];
        #pragma unroll
        for (int j = 0; j < 9; j++) { e[j] = __expf(L[j] - mx); sum += e[j]; }
        float inv = 1.f / sum;
        const float* msb = ms + ((size_t)b * 32 + c) * IMG;
        float accv = ez * inv * zin[((size_t)b * 32 + c) * IMG + h * HW + px];
        #pragma unroll
        for (int kh = 0; kh < 3; kh++) {
            int h2 = h + kh - 1;
            int h2c = min(max(h2, 0), 127);
            bool okh = (unsigned)h2 < 128u;
            #pragma unroll
            for (int kw = 0; kw < 3; kw++) {
                int w2 = px + kw - 1;
                int w2c = min(max(w2, 0), 127);
                bool okw = (unsigned)w2 < 128u;
                float mv = msb[h2c * HW + w2c];
                accv += e[kh * 3 + kw] * inv * ((okh && okw) ? mv : 0.f);
            }
        }
        out[((size_t)b * 32 + c) * IMG + h * HW + px] = accv;
    }
}

// ---------------------------------------------------------------------------
// fuse_strad: cleanup for the 2 straddling channels (c10, c21), all 8
// batches in one dispatch. grid 1024 (b x h), 256 thr = 2 ch x 128 px.
// ---------------------------------------------------------------------------
__global__ __launch_bounds__(256)
void fuse_strad(const _Float16* __restrict__ Ls, const float* __restrict__ ms,
                const float* __restrict__ zin, float* __restrict__ out) {
    int blk = blockIdx.x;
    int b = blk >> 7;
    int h = blk & 127;
    int tid = threadIdx.x;
    int cs = tid >> 7;              // 0 -> c10, 1 -> c21
    int px = tid & 127;
    int c = cs ? 21 : 10;
    int sb = cs ? 9 : 0;

    const _Float16* lrow = Ls + (((size_t)(b * 128 + h) * 18 + sb) * 128) + px;
    float L[9];
    float mx = 0.f;                 // implicit zero logit
    #pragma unroll
    for (int j = 0; j < 9; j++) { L[j] = (float)lrow[j * 128]; mx = fmaxf(mx, L[j]); }
    float ez = __expf(-mx);
    float sum = ez;
    float e[9];
    #pragma unroll
    for (int j = 0; j < 9; j++) { e[j] = __expf(L[j] - mx); sum += e[j]; }
    float inv = 1.f / sum;
    const float* msb = ms + ((size_t)b * 32 + c) * IMG;
    float accv = ez * inv * zin[((size_t)b * 32 + c) * IMG + h * HW + px];
    #pragma unroll
    for (int kh = 0; kh < 3; kh++) {
        int h2 = h + kh - 1;
        int h2c = min(max(h2, 0), 127);
        bool okh = (unsigned)h2 < 128u;
        #pragma unroll
        for (int kw = 0; kw < 3; kw++) {
            int w2 = px + kw - 1;
            int w2c = min(max(w2, 0), 127);
            bool okw = (unsigned)w2 < 128u;
            float mv = msb[h2c * HW + w2c];
            accv += e[kh * 3 + kw] * inv * ((okh && okw) ? mv : 0.f);
        }
    }
    out[((size_t)b * 32 + c) * IMG + h * HW + px] = accv;
}

// ---------------------------------------------------------------------------
extern "C" void kernel_launch(void* const* d_in, const int* in_sizes, int n_in,
                              void* d_out, int out_size, void* d_ws, size_t ws_size,
                              hipStream_t stream) {
    const float* z  = (const float*)d_in[0];
    const float* bb = (const float*)d_in[1];
    const float* ms = (const float*)d_in[2];
    const float* mu = (const float*)d_in[3];
    const float* w0 = (const float*)d_in[4];
    const float* b0 = (const float*)d_in[5];
    const float* w1 = (const float*)d_in[6];
    const float* b1 = (const float*)d_in[7];
    const float* w2 = (const float*)d_in[8];
    const float* b2 = (const float*)d_in[9];
    const float* wl = (const float*)d_in[10];
    const float* bl = (const float*)d_in[11];

    char* ws = (char*)d_ws;
    _Float16* Wp0 = (_Float16*)(ws + 0);          // 184320 (fragment-ordered)
    _Float16* Wp1 = (_Float16*)(ws + 184320);     // 73728 (fragment-ordered)
    _Float16* Wp2 = (_Float16*)(ws + 258048);     // 73728 (fragment-ordered)
    _Float16* WpL = (_Float16*)(ws + 331776);     // 331776 (fragment-ordered)
    _Float16* BufA = (_Float16*)(ws + 663552);    // 43,264,000  (160ch padded)
    _Float16* BufB = (_Float16*)(ws + 43927552);  // 17,305,600  (64ch padded)

    _Float16* X0 = BufA;
    _Float16* Q1 = BufB;
    _Float16* Q2 = BufA;   // overlays X0 (dead after conv0); halo zeroed by
                           // conv_c64 #1 itself (folded)
    _Float16* Q3 = BufB;   // overlays Q1; halo re-zeroed idempotently
    _Float16* Ls = BufA;   // straddle-logit buffer, 8 batches = 4.7 MB

    pack_w_all<<<(331776 + 255) / 256, 256, 0, stream>>>(w0, w1, w2, wl, Wp0, Wp1, Wp2, WpL);
    pack_in<<<1024, 256, 0, stream>>>(z, bb, ms, mu, X0);

    conv3_c160<<<1024, 256, 0, stream>>>(X0, Wp0, b0, Q1);
    conv3_c64<<<1024, 256, 0, stream>>>(Q1, Wp1, b1, Q2);
    conv3_c64<<<1024, 256, 0, stream>>>(Q2, Wp2, b2, Q3);

    head_fused<<<3072, 256, 0, stream>>>(Q3, WpL, bl, ms, z, (float*)d_out, Ls);
    fuse_strad<<<1024, 256, 0, stream>>>(Ls, ms, z, (float*)d_out);
}